// Round 7
// baseline (178.672 us; speedup 1.0000x reference)
//
#include <hip/hip_runtime.h>

typedef _Float16 half8 __attribute__((ext_vector_type(8)));
typedef float f32x4 __attribute__((ext_vector_type(4)));

#define SPH  64           // timesteps per phase
#define NIT  18           // 16 compute phases + 2 pipeline-drain iterations
#define SPKW 392          // spk row stride f16: 384 + 8 pad (784 B rows; +4 banks/row)
#define XSW  32           // xs row stride (floats)
#define C2W  48           // c2L row stride (floats); wave m=2 writes cols 32..47
#define TN   1000

// Software-pipelined, ONE barrier per iteration, SPH=64 to amortize per-iter
// fixed costs (barrier drain, stage-start latency). At iteration ph:
//   waves 0-2: conv+LIF1(ph)   [reads xs[ph&1], writes spk[ph&1]] + stage xs(ph+1)
//   waves 3-5: FC GEMM(ph-1)   [reads spk[(ph-1)&1], writes c2L[(ph-1)&1]]
//              4 t-blocks of 16 steps; 2 acc-pairs per block pass
//   wave 3:    LIF2 scan(ph-2) [reads c2L[(ph-2)&1] == c2L[ph&1]] in 2 chunks,
//              loads hoisted before each MFMA block
// Producer->consumer separated by one barrier; buffer rewrite by two.
// LDS: 100352 + 32768 + 24576 = 157696 B <= 160 KiB (1 block/CU by design).
__global__ __launch_bounds__(384, 1) void snn_fwd(
    const float* __restrict__ x,      // (256,1000,30)
    const float* __restrict__ conv_w, // (16,1,7)
    const float* __restrict__ conv_b, // (16)
    const float* __restrict__ fc_w,   // (35,384)
    const float* __restrict__ fc_b,   // (35)
    float* __restrict__ out)          // (256,35)
{
    __shared__ _Float16 spk[2][SPH][SPKW];   // 100352 B
    __shared__ float    xs[2][SPH][XSW];     //  32768 B
    __shared__ float    c2L[2][SPH][C2W];    //  24576 B

    const int tid  = threadIdx.x;
    const int b    = blockIdx.x;
    const int wid  = tid >> 6;
    const int lane = tid & 63;

    // ---------- conv-wave setup: thread = (c=ct/12, u=ct%12) -> positions 2u,2u+1 ----------
    const int ct = tid;          // 0..191 when wid<3
    const int c  = ct / 12;
    const int u  = ct % 12;
    float wk[7];
    float cb = 0.f;
    if (wid < 3) {
#pragma unroll
        for (int k = 0; k < 7; ++k) wk[k] = conv_w[c * 7 + k];
        cb = conv_b[c];
    }

    // ---------- FC-wave setup: A fragments (f16 weights, K=384) ----------
    const int m  = wid - 3;
    const int nL = lane & 15;    // B col (t_local within 16-block); C col
    const int q  = lane >> 4;    // quad: k = q*8 + j
    half8 A[12];
    if (wid >= 3) {
        const int o = m * 16 + nL;
#pragma unroll
        for (int kt = 0; kt < 12; ++kt) {
            half8 a;
#pragma unroll
            for (int j = 0; j < 8; ++j) {
                int K = kt * 32 + q * 8 + j;
                a[j] = (o < 35) ? (_Float16)fc_w[o * 384 + K] : (_Float16)0.f;
            }
            A[kt] = a;
        }
    }
    const float fcb = (wid == 3 && lane < 35) ? fc_b[lane] : 0.f;

    // ---------- state ----------
    float m10 = 0.f, m11 = 0.f, sp0 = 0.f, sp1 = 0.f;   // LIF1
    float mem2 = 0.f, accO = 0.f;                        // LIF2 (wave3 lanes<35)

    const float* xb = x + (size_t)b * (TN * 30);

    // ---------- prologue: stage xs[0] (1920 floats = 192 thr * 10), t<64<TN ----------
    if (wid < 3) {
#pragma unroll
        for (int r = 0; r < 10; ++r) {
            int f = ct + 192 * r;          // 0..1919
            xs[0][f / 30][f % 30] = xb[f];
        }
    }
    __syncthreads();

#pragma unroll 1
    for (int ph = 0; ph < NIT; ++ph) {
        if (wid < 3) {
            float xr[10];
            const bool stg = (ph <= 14);   // stage phase ph+1 (phases 1..15)
            if (stg) {                     // issue global loads early (latency overlap)
                const float* src = xb + (ph + 1) * (SPH * 30);
#pragma unroll
                for (int r = 0; r < 10; ++r) {
                    int f = ct + 192 * r;
                    int t = (ph + 1) * SPH + f / 30;
                    xr[r] = (t < TN) ? src[f] : 0.f;
                }
            }
            if (ph < 16) {
                const float* xrow = &xs[ph & 1][0][2 * u];
                _Float16* sdst = &spk[ph & 1][0][2 * ct];
#pragma unroll 4
                for (int s = 0; s < SPH; ++s) {
                    const float2* x2 = (const float2*)(xrow + s * XSW);
                    float2 a0 = x2[0], a1 = x2[1], a2 = x2[2], a3 = x2[3];
                    float c1a = cb, c1b = cb;
                    c1a = fmaf(wk[0], a0.x, c1a);  c1b = fmaf(wk[0], a0.y, c1b);
                    c1a = fmaf(wk[1], a0.y, c1a);  c1b = fmaf(wk[1], a1.x, c1b);
                    c1a = fmaf(wk[2], a1.x, c1a);  c1b = fmaf(wk[2], a1.y, c1b);
                    c1a = fmaf(wk[3], a1.y, c1a);  c1b = fmaf(wk[3], a2.x, c1b);
                    c1a = fmaf(wk[4], a2.x, c1a);  c1b = fmaf(wk[4], a2.y, c1b);
                    c1a = fmaf(wk[5], a2.y, c1a);  c1b = fmaf(wk[5], a3.x, c1b);
                    c1a = fmaf(wk[6], a3.x, c1a);  c1b = fmaf(wk[6], a3.y, c1b);

                    m10 = fmaf(0.9f, m10, c1a - sp0);
                    m11 = fmaf(0.9f, m11, c1b - sp1);
                    sp0 = (m10 > 1.0f) ? 1.0f : 0.0f;
                    sp1 = (m11 > 1.0f) ? 1.0f : 0.0f;
                    unsigned pk = (m10 > 1.0f ? 0x3C00u : 0u) | (m11 > 1.0f ? 0x3C000000u : 0u);
                    *(unsigned*)(sdst + s * SPKW) = pk;
                }
            }
            if (stg) {                     // store staged x into the other buffer
                float* dst = &xs[(ph + 1) & 1][0][0];
#pragma unroll
                for (int r = 0; r < 10; ++r) {
                    int f = ct + 192 * r;
                    dst[(f / 30) * XSW + (f % 30)] = xr[r];
                }
            }
        } else {
            const bool doGemm = (ph >= 1 && ph <= 16);
            const bool doScan = (wid == 3 && lane < 35 && ph >= 2);
            const _Float16* sb = &spk[(ph - 1) & 1][0][0];
            float*          cd = &c2L[(ph - 1) & 1][0][0];
            const float*    cs = &c2L[ph & 1][0][0];        // (ph-2)&1 == ph&1

#pragma unroll
            for (int tb = 0; tb < 2; ++tb) {                // 32 timesteps per pass
                // --- scan chunk tb: hoist loads ahead of this pass's MFMAs ---
                float v[32];
                if (doScan) {
#pragma unroll
                    for (int j = 0; j < 32; ++j)
                        v[j] = cs[(tb * 32 + j) * C2W + lane];
                }
                if (doGemm) {
                    const _Float16* sbt = sb + (32 * tb) * SPKW;
                    half8 B0[12], B1[12];
#pragma unroll
                    for (int kt = 0; kt < 12; ++kt) {
                        B0[kt] = *(const half8*)(sbt + nL * SPKW + kt * 32 + q * 8);
                        B1[kt] = *(const half8*)(sbt + (16 + nL) * SPKW + kt * 32 + q * 8);
                    }
                    f32x4 acc0 = {0.f, 0.f, 0.f, 0.f};
                    f32x4 acc1 = {0.f, 0.f, 0.f, 0.f};
#pragma unroll
                    for (int kt = 0; kt < 12; ++kt) {
                        acc0 = __builtin_amdgcn_mfma_f32_16x16x32_f16(A[kt], B0[kt], acc0, 0, 0, 0);
                        acc1 = __builtin_amdgcn_mfma_f32_16x16x32_f16(A[kt], B1[kt], acc1, 0, 0, 0);
                    }
                    // C/D: col = lane&15 (t_local), row = q*4+i (o_local)
                    *(f32x4*)(cd + (32 * tb + nL) * C2W + m * 16 + q * 4)        = acc0;
                    *(f32x4*)(cd + (32 * tb + 16 + nL) * C2W + m * 16 + q * 4)   = acc1;
                }
                if (doScan) {              // LIF2 scan of phase ph-2, chunk tb
                    const int tb0 = (ph - 2) * SPH + tb * 32;
#pragma unroll
                    for (int j = 0; j < 32; ++j) {
                        float r2 = (mem2 > 1.0f) ? 1.0f : 0.0f;
                        mem2 = 0.9f * mem2 + (v[j] + fcb) - r2;
                        if (tb0 + j < TN) accO += mem2;
                    }
                }
            }
        }
        __syncthreads();
    }

    if (wid == 3 && lane < 35) out[b * 35 + lane] = accO * (1.0f / (float)TN);
}

extern "C" void kernel_launch(void* const* d_in, const int* in_sizes, int n_in,
                              void* d_out, int out_size, void* d_ws, size_t ws_size,
                              hipStream_t stream) {
    const float* x      = (const float*)d_in[0];
    const float* conv_w = (const float*)d_in[1];
    const float* conv_b = (const float*)d_in[2];
    const float* fc_w   = (const float*)d_in[3];
    const float* fc_b   = (const float*)d_in[4];
    float* out          = (float*)d_out;

    snn_fwd<<<256, 384, 0, stream>>>(x, conv_w, conv_b, fc_w, fc_b, out);
}